// Round 2
// baseline (671.165 us; speedup 1.0000x reference)
//
#include <hip/hip_runtime.h>

#ifndef INV_CELL_H
#define INV_CELL_H 20.0f
#endif

// Native clang vector type: __builtin_nontemporal_store requires a pointer
// to scalar/vector-of-scalar, not HIP's HIP_vector_type class.
typedef float f32x4 __attribute__((ext_vector_type(4)));

// Cubic B-spline basis + derivative for stencil offset idx in {0,1,2,3},
// where the spline argument is x = f + 1 - idx, f = frac(rel) in [0,1).
// Branches (from the reference's jnp.select) collapse per-offset:
//   idx=0: x in [1,2)   -> b = (2-x)^3/6          = g^3/6,            db = -h*g^2/2
//   idx=1: x in [0,1)   -> b = 2/3 - x^2 + x^3/2  (x=f),              db = -h*f*(2-1.5f)
//   idx=2: x in [-1,0)  -> b = 2/3 - x^2(1+x/2)   = 2/3 - g^2 + g^3/2, db = +h*g*(2-1.5g)
//   idx=3: x in [-2,-1) -> b = (2+x)^3/6          = f^3/6,            db = +h*f^2/2
// with g = 1 - f.  All selects on lane-derived constants -> cndmask, no branches.
__device__ __forceinline__ void spline_eval(float f, float g, int idx,
                                            float& b, float& db) {
    float u  = (idx & 1) ? f : g;          // idx 0,2 use g; idx 1,3 use f
    float u2 = u * u;
    float u3 = u2 * u;
    bool outer = (idx == 0) || (idx == 3); // outer cells: cubic tail
    float b_out = u3 * (1.0f / 6.0f);
    float b_in  = fmaf(0.5f, u3, fmaf(-1.0f, u2, 2.0f / 3.0f)); // 2/3 - u^2 + u^3/2
    b = outer ? b_out : b_in;
    float m_out = 0.5f * u2;               // |db|/h outer
    float m_in  = u * fmaf(-1.5f, u, 2.0f);// u*(2-1.5u) inner
    float mag = outer ? m_out : m_in;
    float sgn = (idx >= 2) ? INV_CELL_H : -INV_CELL_H;
    db = mag * sgn;
}

// Persistent grid-stride kernel. 16 threads per particle: thread slot
// t = lane&15 owns (i,j) = (t>>2, t&3) and vectorizes over all four k.
// Every store is an aligned dwordx4:
//   shapef: float4 at p*64 + t*4              (m = i*16 + j*4 + k = t*4 + k)
//   grad:   3x float4 at p*192 + t*12 floats  (12 consecutive floats per thread)
// Per wave-iteration: 4 particles, 4 KB stored in 4 store instructions
// (the 16 B/lane x 64-lane coalescing maximum). 2048 blocks = 8 blocks/CU
// x 256 CUs resident; each wave loops ~15x, amortizing kernarg/setup and
// keeping the store pipe continuously fed (Guideline 11).
__global__ void __launch_bounds__(256, 8)
cubic_shapefn_kernel(const float* __restrict__ pos,
                     float* __restrict__ shapef,   // [N][64]
                     float* __restrict__ grad,     // [N][64][3]
                     int N) {
    const int t = threadIdx.x & 15;
    const int i = t >> 2;
    const int j = t & 3;
    const int group0  = (int)((blockIdx.x * blockDim.x + threadIdx.x) >> 4);
    const int ngroups = (int)((gridDim.x * blockDim.x) >> 4);

    for (int p = group0; p < N; p += ngroups) {
        // 16 lanes per particle read the same 3 floats; L1 broadcasts.
        float px = pos[(size_t)p * 3 + 0];
        float py = pos[(size_t)p * 3 + 1];
        float pz = pos[(size_t)p * 3 + 2];

        float rx = px * INV_CELL_H, ry = py * INV_CELL_H, rz = pz * INV_CELL_H;
        float fx = rx - floorf(rx), fy = ry - floorf(ry), fz = rz - floorf(rz);
        float gx = 1.0f - fx,       gy = 1.0f - fy,       gz = 1.0f - fz;

        float bx, dbx, by, dby;
        spline_eval(fx, gx, i, bx, dbx);
        spline_eval(fy, gy, j, by, dby);

        float bz[4], dbz[4];
#pragma unroll
        for (int k = 0; k < 4; ++k) spline_eval(fz, gz, k, bz[k], dbz[k]);

        float A  = bx * by;     // shapef & d/dz factor
        float Bx = dbx * by;    // d/dx factor
        float By = bx * dby;    // d/dy factor

        f32x4 sv = { A * bz[0], A * bz[1], A * bz[2], A * bz[3] };

        float gxk[4], gyk[4], gzk[4];
#pragma unroll
        for (int k = 0; k < 4; ++k) {
            gxk[k] = Bx * bz[k];
            gyk[k] = By * bz[k];
            gzk[k] = A  * dbz[k];
        }
        // 12 consecutive grad floats for m = t*4 .. t*4+3, packed as 3 float4s.
        f32x4 q0 = { gxk[0], gyk[0], gzk[0], gxk[1] };
        f32x4 q1 = { gyk[1], gzk[1], gxk[2], gyk[2] };
        f32x4 q2 = { gzk[2], gxk[3], gyk[3], gzk[3] };

        // Write-once 512 MB stream: nontemporal keeps it out of L2's way.
        __builtin_nontemporal_store(sv, (f32x4*)(shapef + (size_t)p * 64 + t * 4));
        float* gbase = grad + (size_t)p * 192 + t * 12;   // byte off p*768 + t*48, 16B-aligned
        __builtin_nontemporal_store(q0, (f32x4*)(gbase + 0));
        __builtin_nontemporal_store(q1, (f32x4*)(gbase + 4));
        __builtin_nontemporal_store(q2, (f32x4*)(gbase + 8));
    }
}

extern "C" void kernel_launch(void* const* d_in, const int* in_sizes, int n_in,
                              void* d_out, int out_size, void* d_ws, size_t ws_size,
                              hipStream_t stream) {
    const float* pos = (const float*)d_in[0];
    int N = in_sizes[0] / 3;                       // 500,000
    float* shapef = (float*)d_out;                 // [N*64]
    float* grad   = shapef + (size_t)N * 64;       // [N*64*3]
    int needed = (N + 15) / 16;                    // 16 particles per 256-thread block
    int blocks = 2048;                             // 8 blocks/CU x 256 CUs, grid-stride
    if (blocks > needed) blocks = needed;
    cubic_shapefn_kernel<<<blocks, 256, 0, stream>>>(pos, shapef, grad, N);
}